// Round 6
// baseline (193.563 us; speedup 1.0000x reference)
//
#include <hip/hip_runtime.h>

#define NB 64
#define NN 512
#define ED 128
#define NF 128
#define PAD_ID 49999

typedef unsigned short ushort_t;
typedef __attribute__((ext_vector_type(8))) short short8v;
typedef __attribute__((ext_vector_type(4))) float f32x4;

__device__ __forceinline__ unsigned short f2b(float f) {
    unsigned int u = __float_as_uint(f);
    u = (u + 0x7fffu + ((u >> 16) & 1u)) >> 16;
    return (unsigned short)u;
}
__device__ __forceinline__ float b2f(unsigned short h) {
    return __uint_as_float(((unsigned int)h) << 16);
}

// ---------------- Kernel 1: h_T(bf16) = (emb[doc] @ W)^T, e_src, e_dst ----------------
// 1024 blocks x 256 threads; block = 32 tokens. Thread = 4 tokens x 4 feats.
__global__ __launch_bounds__(256) void k_h(
    const int* __restrict__ doc, const float* __restrict__ emb,
    const float* __restrict__ W, const float* __restrict__ a_src,
    const float* __restrict__ a_dst, ushort_t* __restrict__ hT,
    float* __restrict__ esrc, float* __restrict__ edst)
{
    __shared__ float wl[32][128];      // 16 KB gathered embeddings
    const int tid = threadIdx.x;
    const int t0  = blockIdx.x * 32;
    const int b   = t0 >> 9;
    const int tl0 = t0 & (NN - 1);

    // gather: 32 tokens x 32 float4 = 1024 float4
#pragma unroll
    for (int k = 0; k < 4; ++k) {
        int idx = tid + k * 256;
        int tok = idx >> 5;
        int e4  = (idx & 31) << 2;
        int d   = doc[t0 + tok];
        *(float4*)&wl[tok][e4] = *(const float4*)(emb + (size_t)d * ED + e4);
    }
    __syncthreads();

    const int fg = tid & 31;  const int f0 = fg << 2;   // feats f0..f0+3
    const int tg = tid >> 5;                            // tokens tg*4..tg*4+3

    float acc[4][4] = {};
    for (int e = 0; e < 128; e += 4) {
        float4 wr[4];
#pragma unroll
        for (int k = 0; k < 4; ++k)
            wr[k] = *(const float4*)(W + (e + k) * NF + f0);
#pragma unroll
        for (int r = 0; r < 4; ++r) {
            const float4 x = *(const float4*)&wl[tg * 4 + r][e];
            const float xa[4] = {x.x, x.y, x.z, x.w};
#pragma unroll
            for (int k = 0; k < 4; ++k) {
                acc[r][0] = fmaf(xa[k], wr[k].x, acc[r][0]);
                acc[r][1] = fmaf(xa[k], wr[k].y, acc[r][1]);
                acc[r][2] = fmaf(xa[k], wr[k].z, acc[r][2]);
                acc[r][3] = fmaf(xa[k], wr[k].w, acc[r][3]);
            }
        }
    }

    const float4 as = *(const float4*)(a_src + f0);
    const float4 ad = *(const float4*)(a_dst + f0);
#pragma unroll
    for (int r = 0; r < 4; ++r) {
        float es = acc[r][0]*as.x + acc[r][1]*as.y + acc[r][2]*as.z + acc[r][3]*as.w;
        float ed = acc[r][0]*ad.x + acc[r][1]*ad.y + acc[r][2]*ad.z + acc[r][3]*ad.w;
#pragma unroll
        for (int off = 1; off < 32; off <<= 1) {
            es += __shfl_xor(es, off);
            ed += __shfl_xor(ed, off);
        }
        if (fg == 0) {
            esrc[t0 + tg * 4 + r] = es;
            edst[t0 + tg * 4 + r] = ed;
        }
    }

    // write h_T bf16: [b][f][j], 4 consecutive tokens per 8B store
#pragma unroll
    for (int c = 0; c < 4; ++c) {
        union { ushort_t u[4]; uint2 v; } pk;
#pragma unroll
        for (int r = 0; r < 4; ++r) pk.u[r] = f2b(acc[r][c]);
        *(uint2*)(hT + (size_t)b * NF * NN + (size_t)(f0 + c) * NN + tl0 + tg * 4) = pk.v;
    }
}

// ------------- Kernel 2: attention + MFMA PV + pool partials -------------
// grid (32, 64) x 256 threads; block = 16 rows; wave w covers cols [w*128,(w+1)*128)
// for softmax, then PV full-K for feats [w*32,(w+1)*32).
__global__ __launch_bounds__(256, 6) void k_attn(
    const int* __restrict__ doc, const ushort_t* __restrict__ hT,
    const float* __restrict__ esrc, const float* __restrict__ edst,
    float* __restrict__ out_att, float* __restrict__ out_sent,
    float* __restrict__ pool)
{
    __shared__ float edl[NN];            // pad cols encoded as -3e30
    __shared__ float esl[16], rvl[16], invl[16];
    __shared__ float mx[4][16], sx[4][16];
    __shared__ ushort_t p_l[16][520];    // bf16 p, padded stride (2-way conflicts only)

    const int tid = threadIdx.x;
    const int b   = blockIdx.y;
    const int i0  = blockIdx.x * 16;

#pragma unroll
    for (int k = 0; k < 2; ++k) {
        int j = tid + k * 256;
        float ed = edst[b * NN + j];
        edl[j] = (doc[b * NN + j] == PAD_ID) ? -3e30f : ed;
    }
    if (tid < 16) {
        esl[tid] = esrc[b * NN + i0 + tid];
        rvl[tid] = (doc[b * NN + i0 + tid] == PAD_ID) ? 0.f : 1.f;
    }
    __syncthreads();

    const int w    = tid >> 6;
    const int lane = tid & 63;
    const int mr   = lane & 15;      // row within block tile
    const int grp  = lane >> 4;      // k-group 0..3
    const int c0   = w * 128;        // wave's softmax column window
    const float es = esl[mr];
    const bool  rv = rvl[mr] != 0.f;

    // ---- pass 1: partial row max over this wave's 128 cols ----
    float m = -1e30f;
#pragma unroll
    for (int ks = 0; ks < 4; ++ks) {
        const int j0 = c0 + ks * 32 + grp * 8;
        const float4 e0 = *(const float4*)&edl[j0], e1 = *(const float4*)&edl[j0 + 4];
        const float xs[8] = {es+e0.x, es+e0.y, es+e0.z, es+e0.w,
                             es+e1.x, es+e1.y, es+e1.z, es+e1.w};
#pragma unroll
        for (int q = 0; q < 8; ++q)
            if (xs[q] > -1e20f) m = fmaxf(m, fmaxf(xs[q], 0.f));
    }
    m = fmaxf(m, __shfl_xor(m, 16));
    m = fmaxf(m, __shfl_xor(m, 32));
    if (lane < 16) mx[w][mr] = m;
    __syncthreads();
    m = fmaxf(fmaxf(mx[0][mr], mx[1][mr]), fmaxf(mx[2][mr], mx[3][mr]));

    // ---- pass 2: p = exp(x-m) (1 for all-pad rows), pack bf16, partial sum ----
    float s = 0.f;
    unsigned int pb[16];
#pragma unroll
    for (int ks = 0; ks < 4; ++ks) {
        const int j0 = c0 + ks * 32 + grp * 8;
        const float4 e0 = *(const float4*)&edl[j0], e1 = *(const float4*)&edl[j0 + 4];
        const float xs[8] = {es+e0.x, es+e0.y, es+e0.z, es+e0.w,
                             es+e1.x, es+e1.y, es+e1.z, es+e1.w};
        float p[8];
#pragma unroll
        for (int q = 0; q < 8; ++q) {
            float pv;
            if (rv) pv = (xs[q] > -1e20f) ? __expf(fmaxf(xs[q], 0.f) - m) : 0.f;
            else    pv = 1.f;
            p[q] = pv; s += pv;
        }
        union { unsigned int u[4]; uint4 v; } pk;
#pragma unroll
        for (int q = 0; q < 4; ++q)
            pk.u[q] = ((unsigned)f2b(p[2*q+1]) << 16) | (unsigned)f2b(p[2*q]);
        pb[ks*4+0] = pk.u[0]; pb[ks*4+1] = pk.u[1];
        pb[ks*4+2] = pk.u[2]; pb[ks*4+3] = pk.u[3];
        *(uint4*)&p_l[mr][j0] = pk.v;
    }
    s += __shfl_xor(s, 16);
    s += __shfl_xor(s, 32);
    if (lane < 16) sx[w][mr] = s;
    __syncthreads();
    s = sx[0][mr] + sx[1][mr] + sx[2][mr] + sx[3][mr];
    const float inv = rv ? (1.f / s) : (1.f / 512.f);
    if (w == 0 && lane < 16) invl[mr] = inv;

    // ---- att write (from regs) ----
    float* arow = out_att + ((size_t)(b * NN + i0 + mr)) * NN + c0;
#pragma unroll
    for (int ks = 0; ks < 4; ++ks) {
        float4 o0, o1;
        o0.x = b2f((ushort_t)(pb[ks*4+0] & 0xffff)) * inv;
        o0.y = b2f((ushort_t)(pb[ks*4+0] >> 16))    * inv;
        o0.z = b2f((ushort_t)(pb[ks*4+1] & 0xffff)) * inv;
        o0.w = b2f((ushort_t)(pb[ks*4+1] >> 16))    * inv;
        o1.x = b2f((ushort_t)(pb[ks*4+2] & 0xffff)) * inv;
        o1.y = b2f((ushort_t)(pb[ks*4+2] >> 16))    * inv;
        o1.z = b2f((ushort_t)(pb[ks*4+3] & 0xffff)) * inv;
        o1.w = b2f((ushort_t)(pb[ks*4+3] >> 16))    * inv;
        *(float4*)(arow + ks * 32 + grp * 8)     = o0;
        *(float4*)(arow + ks * 32 + grp * 8 + 4) = o1;
    }
    __syncthreads();   // p_l + invl visible

    // ---- PV: wave w computes feats [w*32, w*32+32) over full K=512 ----
    const ushort_t* hTb = hT + (size_t)b * NF * NN;
#pragma unroll
    for (int t = 0; t < 2; ++t) {
        const int n0 = (w * 2 + t) * 16;
        f32x4 acc = {0.f, 0.f, 0.f, 0.f};
        const ushort_t* bp = hTb + (size_t)(n0 + mr) * NN + grp * 8;
        const ushort_t* ap = &p_l[mr][grp * 8];
#pragma unroll
        for (int ks = 0; ks < 16; ++ks) {
            const short8v av = *(const short8v*)(ap + ks * 32);
            const short8v bv = *(const short8v*)(bp + ks * 32);
            acc = __builtin_amdgcn_mfma_f32_16x16x32_bf16(av, bv, acc, 0, 0, 0);
        }
        const int feat = n0 + mr;        // C/D: col = lane&15
        float psum = 0.f;
#pragma unroll
        for (int reg = 0; reg < 4; ++reg) {
            const int rl = grp * 4 + reg;    // C/D: row = (lane>>4)*4+reg
            float v = acc[reg] * invl[rl];
            v = v > 0.f ? v : expm1f(v);
            out_sent[((size_t)(b * NN + i0 + rl)) * NF + feat] = v;
            psum += v;
        }
        psum += __shfl_xor(psum, 16);
        psum += __shfl_xor(psum, 32);
        if (lane < 16) atomicAdd(&pool[b * NF + feat], psum);
    }
}

// ---------------- Kernel 3: pool output + label softmax (axis=0 = batch) ----------------
__global__ __launch_bounds__(128) void k_label(
    const float* __restrict__ poolAccum, const float* __restrict__ Wc,
    const float* __restrict__ bc, float* __restrict__ out_pool,
    float* __restrict__ out_label)
{
    __shared__ float wc0[NF], wc1[NF];
    const int tid = threadIdx.x;
    if (tid < NF) { wc0[tid] = Wc[tid * 2]; wc1[tid] = Wc[tid * 2 + 1]; }
    __syncthreads();

    for (int i = tid; i < NB * NF / 4; i += 128) {
        float4 v = *(const float4*)(poolAccum + i * 4);
        v.x *= (1.f/512.f); v.y *= (1.f/512.f); v.z *= (1.f/512.f); v.w *= (1.f/512.f);
        *(float4*)(out_pool + i * 4) = v;
    }

    const int b = tid & 63, c = tid >> 6;    // wave 0: label 0, wave 1: label 1
    const float* pbp = poolAccum + b * NF;
    const float* wcp = c ? wc1 : wc0;
    float z = bc[c];
    for (int f = 0; f < NF; f += 4) {
        const float4 pv = *(const float4*)(pbp + f);
        z = fmaf(pv.x * (1.f/512.f), wcp[f + 0], z);
        z = fmaf(pv.y * (1.f/512.f), wcp[f + 1], z);
        z = fmaf(pv.z * (1.f/512.f), wcp[f + 2], z);
        z = fmaf(pv.w * (1.f/512.f), wcp[f + 3], z);
    }
    float mz = z;
#pragma unroll
    for (int off = 32; off; off >>= 1) mz = fmaxf(mz, __shfl_xor(mz, off));
    float e = __expf(z - mz);
    float sv = e;
#pragma unroll
    for (int off = 32; off; off >>= 1) sv += __shfl_xor(sv, off);
    out_label[b * 2 + c] = e / sv;
}

extern "C" void kernel_launch(void* const* d_in, const int* in_sizes, int n_in,
                              void* d_out, int out_size, void* d_ws, size_t ws_size,
                              hipStream_t stream)
{
    const int*   doc   = (const int*)d_in[0];
    const float* emb   = (const float*)d_in[1];
    const float* W     = (const float*)d_in[2];
    const float* a_src = (const float*)d_in[3];
    const float* a_dst = (const float*)d_in[4];
    const float* Wc    = (const float*)d_in[5];
    const float* bc    = (const float*)d_in[6];

    float* out       = (float*)d_out;
    float* out_pool  = out;
    float* out_att   = out_pool + NB * NF;
    float* out_sent  = out_att + (size_t)NB * NN * NN;
    float* out_label = out_sent + (size_t)NB * NN * NF;

    char* base = (char*)d_ws;
    ushort_t* hT  = (ushort_t*)base;                              // 8 MB bf16
    float* esrc   = (float*)(base + (size_t)NB * NF * NN * 2);
    float* edst   = esrc + NB * NN;
    float* pool   = edst + NB * NN;

    hipMemsetAsync(pool, 0, NB * NF * sizeof(float), stream);

    k_h<<<(NB * NN) / 32, 256, 0, stream>>>(doc, emb, W, a_src, a_dst, hT, esrc, edst);

    dim3 g2(NN / 16, NB);
    k_attn<<<g2, 256, 0, stream>>>(doc, hT, esrc, edst, out_att, out_sent, pool);

    k_label<<<1, 128, 0, stream>>>(pool, Wc, bc, out_pool, out_label);
}

// Round 7
// 174.463 us; speedup vs baseline: 1.1095x; 1.1095x over previous
//
#include <hip/hip_runtime.h>

#define NB 64
#define NN 512
#define ED 128
#define NF 128
#define PAD_ID 49999

typedef unsigned short ushort_t;
typedef __attribute__((ext_vector_type(8))) short short8v;
typedef __attribute__((ext_vector_type(4))) float f32x4;

__device__ __forceinline__ unsigned short f2b(float f) {
    unsigned int u = __float_as_uint(f);
    u = (u + 0x7fffu + ((u >> 16) & 1u)) >> 16;
    return (unsigned short)u;
}
__device__ __forceinline__ float b2f(unsigned short h) {
    return __uint_as_float(((unsigned int)h) << 16);
}

// ---------------- Kernel 1: h_T(bf16) = (emb[doc] @ W)^T, e_src, e_dst ----------------
// 1024 blocks x 256 threads; block = 32 tokens. Thread = 4 tokens x 4 feats.
__global__ __launch_bounds__(256) void k_h(
    const int* __restrict__ doc, const float* __restrict__ emb,
    const float* __restrict__ W, const float* __restrict__ a_src,
    const float* __restrict__ a_dst, ushort_t* __restrict__ hT,
    float* __restrict__ esrc, float* __restrict__ edst)
{
    __shared__ float wl[32][128];      // 16 KB gathered embeddings
    const int tid = threadIdx.x;
    const int t0  = blockIdx.x * 32;
    const int b   = t0 >> 9;
    const int tl0 = t0 & (NN - 1);

#pragma unroll
    for (int k = 0; k < 4; ++k) {
        int idx = tid + k * 256;
        int tok = idx >> 5;
        int e4  = (idx & 31) << 2;
        int d   = doc[t0 + tok];
        *(float4*)&wl[tok][e4] = *(const float4*)(emb + (size_t)d * ED + e4);
    }
    __syncthreads();

    const int fg = tid & 31;  const int f0 = fg << 2;
    const int tg = tid >> 5;

    float acc[4][4] = {};
    for (int e = 0; e < 128; e += 4) {
        float4 wr[4];
#pragma unroll
        for (int k = 0; k < 4; ++k)
            wr[k] = *(const float4*)(W + (e + k) * NF + f0);
#pragma unroll
        for (int r = 0; r < 4; ++r) {
            const float4 x = *(const float4*)&wl[tg * 4 + r][e];
            const float xa[4] = {x.x, x.y, x.z, x.w};
#pragma unroll
            for (int k = 0; k < 4; ++k) {
                acc[r][0] = fmaf(xa[k], wr[k].x, acc[r][0]);
                acc[r][1] = fmaf(xa[k], wr[k].y, acc[r][1]);
                acc[r][2] = fmaf(xa[k], wr[k].z, acc[r][2]);
                acc[r][3] = fmaf(xa[k], wr[k].w, acc[r][3]);
            }
        }
    }

    const float4 as = *(const float4*)(a_src + f0);
    const float4 ad = *(const float4*)(a_dst + f0);
#pragma unroll
    for (int r = 0; r < 4; ++r) {
        float es = acc[r][0]*as.x + acc[r][1]*as.y + acc[r][2]*as.z + acc[r][3]*as.w;
        float ed = acc[r][0]*ad.x + acc[r][1]*ad.y + acc[r][2]*ad.z + acc[r][3]*ad.w;
#pragma unroll
        for (int off = 1; off < 32; off <<= 1) {
            es += __shfl_xor(es, off);
            ed += __shfl_xor(ed, off);
        }
        if (fg == 0) {
            esrc[t0 + tg * 4 + r] = es;
            edst[t0 + tg * 4 + r] = ed;
        }
    }

#pragma unroll
    for (int c = 0; c < 4; ++c) {
        union { ushort_t u[4]; uint2 v; } pk;
#pragma unroll
        for (int r = 0; r < 4; ++r) pk.u[r] = f2b(acc[r][c]);
        *(uint2*)(hT + (size_t)b * NF * NN + (size_t)(f0 + c) * NN + tl0 + tg * 4) = pk.v;
    }
}

// ------------- Kernel 2: attention + MFMA PV + pool partials -------------
// grid (16, 64) x 256 threads; block = 32 rows.
// Phase 1 (softmax): wave w owns rows w*8..w*8+7 over ALL 512 cols -> p_l (bf16).
// Phase 2 (att write): full-contiguous 1KB stores from LDS.
// Phase 3 (PV): wave (rt=w&1, fh=w>>1) -> rows rt*16.., feats fh*64.. via MFMA.
__global__ __launch_bounds__(256, 4) void k_attn(
    const int* __restrict__ doc, const ushort_t* __restrict__ hT,
    const float* __restrict__ esrc, const float* __restrict__ edst,
    float* __restrict__ out_att, float* __restrict__ out_sent,
    float* __restrict__ pool)
{
    __shared__ float edl[NN];              // pad cols = -3e30
    __shared__ float esl[32], rvl[32], invl[32];
    __shared__ ushort_t p_l[32][520];      // bf16 p; stride 520 => conflict-free groups

    const int tid = threadIdx.x;
    const int b   = blockIdx.y;
    const int i0  = blockIdx.x * 32;

#pragma unroll
    for (int k = 0; k < 2; ++k) {
        int j = tid + k * 256;
        edl[j] = (doc[b * NN + j] == PAD_ID) ? -3e30f : edst[b * NN + j];
    }
    if (tid < 32) {
        esl[tid] = esrc[b * NN + i0 + tid];
        rvl[tid] = (doc[b * NN + i0 + tid] == PAD_ID) ? 0.f : 1.f;
    }
    __syncthreads();

    const int w    = tid >> 6;
    const int lane = tid & 63;

    // ---- Phase 1: softmax. wave w: rows w*8+rl, rl=lane&7; col slice kg=lane>>3 ----
    {
        const int rl  = lane & 7;
        const int kg  = lane >> 3;            // 8 col-groups of 8
        const int row = w * 8 + rl;
        const float es = esl[row];
        const bool  rv = rvl[row] != 0.f;

        float m = -1e30f;
#pragma unroll
        for (int ks = 0; ks < 8; ++ks) {
            const int j0 = kg * 8 + ks * 64;
            const float4 e0 = *(const float4*)&edl[j0], e1 = *(const float4*)&edl[j0 + 4];
            // pads give relu->0 which never exceeds true max (diag col valid => m>=0)
            m = fmaxf(m, fmaxf(fmaxf(fmaxf(es+e0.x,es+e0.y),fmaxf(es+e0.z,es+e0.w)),
                               fmaxf(fmaxf(es+e1.x,es+e1.y),fmaxf(es+e1.z,es+e1.w))));
        }
        m = fmaxf(m, 0.f);
        m = fmaxf(m, __shfl_xor(m, 8));
        m = fmaxf(m, __shfl_xor(m, 16));
        m = fmaxf(m, __shfl_xor(m, 32));

        float s = 0.f;
#pragma unroll
        for (int ks = 0; ks < 8; ++ks) {
            const int j0 = kg * 8 + ks * 64;
            const float4 e0 = *(const float4*)&edl[j0], e1 = *(const float4*)&edl[j0 + 4];
            const float xs[8] = {es+e0.x, es+e0.y, es+e0.z, es+e0.w,
                                 es+e1.x, es+e1.y, es+e1.z, es+e1.w};
            float p[8];
#pragma unroll
            for (int q = 0; q < 8; ++q) {
                float pv;
                if (rv) pv = (xs[q] > -1e20f) ? __expf(fmaxf(xs[q], 0.f) - m) : 0.f;
                else    pv = 1.f;
                p[q] = pv; s += pv;
            }
            union { unsigned int u[4]; uint4 v; } pk;
#pragma unroll
            for (int q = 0; q < 4; ++q)
                pk.u[q] = ((unsigned)f2b(p[2*q+1]) << 16) | (unsigned)f2b(p[2*q]);
            *(uint4*)&p_l[row][j0] = pk.v;
        }
        s += __shfl_xor(s, 8);
        s += __shfl_xor(s, 16);
        s += __shfl_xor(s, 32);
        if (kg == 0) invl[row] = rv ? (1.f / s) : (1.f / 512.f);
    }
    __syncthreads();

    // ---- Phase 2: att f32 write, fully contiguous (1KB per store instruction) ----
#pragma unroll
    for (int r8 = 0; r8 < 8; ++r8) {
        const int r = w * 8 + r8;
        const float inv = invl[r];
        float* arow = out_att + ((size_t)(b * NN + i0 + r)) * NN;
#pragma unroll
        for (int half = 0; half < 2; ++half) {
            const uint2 v = *(const uint2*)&p_l[r][half * 256 + lane * 4];
            float4 o;
            o.x = b2f((ushort_t)(v.x & 0xffff)) * inv;
            o.y = b2f((ushort_t)(v.x >> 16))    * inv;
            o.z = b2f((ushort_t)(v.y & 0xffff)) * inv;
            o.w = b2f((ushort_t)(v.y >> 16))    * inv;
            *(float4*)(arow + half * 256 + lane * 4) = o;
        }
    }

    // ---- Phase 3: PV via MFMA. wave w -> rt=w&1 (rows), fh=w>>1 (feats) ----
    const int mr  = lane & 15;
    const int grp = lane >> 4;
    const int rt  = w & 1;
    const int fh  = w >> 1;

    short8v a_regs[16];
#pragma unroll
    for (int ks = 0; ks < 16; ++ks)
        a_regs[ks] = *(const short8v*)&p_l[rt * 16 + mr][grp * 8 + ks * 32];

    const ushort_t* hTb = hT + (size_t)b * NF * NN;
#pragma unroll
    for (int t = 0; t < 4; ++t) {
        const int n0 = (fh * 4 + t) * 16;
        f32x4 acc = {0.f, 0.f, 0.f, 0.f};
        const ushort_t* bp = hTb + (size_t)(n0 + mr) * NN + grp * 8;
#pragma unroll
        for (int ks = 0; ks < 16; ++ks) {
            const short8v bv = *(const short8v*)(bp + ks * 32);
            acc = __builtin_amdgcn_mfma_f32_16x16x32_bf16(a_regs[ks], bv, acc, 0, 0, 0);
        }
        const int feat = n0 + mr;            // C/D: col = lane&15
        float psum = 0.f;
#pragma unroll
        for (int reg = 0; reg < 4; ++reg) {
            const int rl2 = rt * 16 + grp * 4 + reg;   // C/D: row = (lane>>4)*4+reg
            float v = acc[reg] * invl[rl2];
            v = v > 0.f ? v : expm1f(v);
            out_sent[((size_t)(b * NN + i0 + rl2)) * NF + feat] = v;
            psum += v;
        }
        psum += __shfl_xor(psum, 16);
        psum += __shfl_xor(psum, 32);
        if (lane < 16) atomicAdd(&pool[b * NF + feat], psum);
    }
}

// ---------------- Kernel 3: pool output + label softmax (axis=0 = batch) ----------------
__global__ __launch_bounds__(128) void k_label(
    const float* __restrict__ poolAccum, const float* __restrict__ Wc,
    const float* __restrict__ bc, float* __restrict__ out_pool,
    float* __restrict__ out_label)
{
    __shared__ float wc0[NF], wc1[NF];
    const int tid = threadIdx.x;
    if (tid < NF) { wc0[tid] = Wc[tid * 2]; wc1[tid] = Wc[tid * 2 + 1]; }
    __syncthreads();

    for (int i = tid; i < NB * NF / 4; i += 128) {
        float4 v = *(const float4*)(poolAccum + i * 4);
        v.x *= (1.f/512.f); v.y *= (1.f/512.f); v.z *= (1.f/512.f); v.w *= (1.f/512.f);
        *(float4*)(out_pool + i * 4) = v;
    }

    const int b = tid & 63, c = tid >> 6;
    const float* pbp = poolAccum + b * NF;
    const float* wcp = c ? wc1 : wc0;
    float z = bc[c];
    for (int f = 0; f < NF; f += 4) {
        const float4 pv = *(const float4*)(pbp + f);
        z = fmaf(pv.x * (1.f/512.f), wcp[f + 0], z);
        z = fmaf(pv.y * (1.f/512.f), wcp[f + 1], z);
        z = fmaf(pv.z * (1.f/512.f), wcp[f + 2], z);
        z = fmaf(pv.w * (1.f/512.f), wcp[f + 3], z);
    }
    float mz = z;
#pragma unroll
    for (int off = 32; off; off >>= 1) mz = fmaxf(mz, __shfl_xor(mz, off));
    float e = __expf(z - mz);
    float sv = e;
#pragma unroll
    for (int off = 32; off; off >>= 1) sv += __shfl_xor(sv, off);
    out_label[b * 2 + c] = e / sv;
}

extern "C" void kernel_launch(void* const* d_in, const int* in_sizes, int n_in,
                              void* d_out, int out_size, void* d_ws, size_t ws_size,
                              hipStream_t stream)
{
    const int*   doc   = (const int*)d_in[0];
    const float* emb   = (const float*)d_in[1];
    const float* W     = (const float*)d_in[2];
    const float* a_src = (const float*)d_in[3];
    const float* a_dst = (const float*)d_in[4];
    const float* Wc    = (const float*)d_in[5];
    const float* bc    = (const float*)d_in[6];

    float* out       = (float*)d_out;
    float* out_pool  = out;
    float* out_att   = out_pool + NB * NF;
    float* out_sent  = out_att + (size_t)NB * NN * NN;
    float* out_label = out_sent + (size_t)NB * NN * NF;

    char* base = (char*)d_ws;
    ushort_t* hT  = (ushort_t*)base;                              // 8 MB bf16
    float* esrc   = (float*)(base + (size_t)NB * NF * NN * 2);
    float* edst   = esrc + NB * NN;
    float* pool   = edst + NB * NN;

    hipMemsetAsync(pool, 0, NB * NF * sizeof(float), stream);

    k_h<<<(NB * NN) / 32, 256, 0, stream>>>(doc, emb, W, a_src, a_dst, hT, esrc, edst);

    dim3 g2(NN / 32, NB);
    k_attn<<<g2, 256, 0, stream>>>(doc, hT, esrc, edst, out_att, out_sent, pool);

    k_label<<<1, 128, 0, stream>>>(pool, Wc, bc, out_pool, out_label);
}